// Round 15
// baseline (565.515 us; speedup 1.0000x reference)
//
#include <hip/hip_runtime.h>
#include <hip/hip_bf16.h>
#include <stdint.h>

// ---------------------------------------------------------------------------
// MGCNN on MI355X — 2-product f16 MFMA conv + all-f16 MFMA gate kernel.
//
// Number format: B operands dual-level (b = b1 + b2*2^-11), A single f16.
//   acc1 = sum a1*b1 ; acc2 = sum a1*b2 ; D = acc1 + acc2*2^-11
//
// R15: LSTM cell state c stored f16 (was fp32). Gate WRITE_SIZE was 113 MB
// = c-fp32 75.5 + h-f16 37.7; c reads hit L3 but writes stream to HBM.
// f16 c rounding ~2^-11/iter on O(1) values — well below the 0.031 floor.
// Engine (double-buffered LDS, R14) unchanged.
// ---------------------------------------------------------------------------

#define DIM 768
#define MXK 589824        // 768*768
#define STK 2949120       // 5*768*768
#define RSCALE 2048.0f
#define RINV   (1.0f / 2048.0f)

typedef _Float16 f16x8 __attribute__((ext_vector_type(8)));
typedef float f32x4 __attribute__((ext_vector_type(4)));
typedef unsigned short ushort_t;
typedef _Float16 f16_t;

__device__ __forceinline__ float sigm(float v) {
    float e = __expf(-v);
    return __builtin_amdgcn_rcpf(1.0f + e);   // raw v_rcp_f32, ~1 ulp
}
__device__ __forceinline__ void split2h(float f, f16_t& h1, f16_t& h2) {
    h1 = (f16_t)f;
    float r = f - (float)h1;
    h2 = (f16_t)(r * RSCALE);
}

// async 16B global->LDS (LDS dest = wave-uniform base + lane*16)
__device__ __forceinline__ void gl_lds16(const f16_t* g, f16_t* l) {
    auto gp = reinterpret_cast<const __attribute__((address_space(1))) uint32_t*>(
        reinterpret_cast<uintptr_t>(g));
    auto lp = reinterpret_cast<__attribute__((address_space(3))) uint32_t*>(
        reinterpret_cast<uintptr_t>(l));
    __builtin_amdgcn_global_load_lds(gp, lp, 16, 0, 0);
}

// ---------------------------------------------------------------------------
// init: T0 = I, T1 = L  ->  f16x2s, Tr stack then Tc stack per level
// ---------------------------------------------------------------------------
__global__ __launch_bounds__(256) void init_split(
    const float* __restrict__ Lrow, const float* __restrict__ Lcol,
    f16_t* __restrict__ S0, f16_t* __restrict__ S1)
{
    int idx = blockIdx.x * 256 + threadIdx.x;
    int p = idx / DIM, m = idx % DIM;
    f16_t eye = (p == m) ? (f16_t)1.0f : (f16_t)0.0f;
    S0[idx] = eye; S1[idx] = (f16_t)0.0f;
    S0[STK + idx] = eye; S1[STK + idx] = (f16_t)0.0f;
    f16_t h1, h2;
    split2h(Lrow[idx], h1, h2);
    S0[MXK + idx] = h1; S1[MXK + idx] = h2;
    split2h(Lcol[idx], h1, h2);
    S0[STK + MXK + idx] = h1; S1[STK + MXK + idx] = h2;
}

// ---------------------------------------------------------------------------
// prep: Wstack f16 [128 R][64 k] and thstack f16 [32 o][32 k=ij] (k>=25 -> 0)
// ---------------------------------------------------------------------------
__global__ __launch_bounds__(256) void prep_gate(
    const float* __restrict__ Wf, const float* __restrict__ Wi,
    const float* __restrict__ Wo, const float* __restrict__ Wc,
    const float* __restrict__ Uf, const float* __restrict__ Ui,
    const float* __restrict__ Uo, const float* __restrict__ Uc,
    const float* __restrict__ theta,
    f16_t* __restrict__ Wstack, f16_t* __restrict__ thstack)
{
    int idx = blockIdx.x * 256 + threadIdx.x;
    if (idx < 8192) {
        int R = idx >> 6, k = idx & 63;
        int g = (R >> 4) & 3, o = (R >> 6) * 16 + (R & 15);
        const float* Wg[4] = {Wf, Wi, Wo, Wc};
        const float* Ug[4] = {Uf, Ui, Uo, Uc};
        float v = (k < 32) ? Wg[g][k * 32 + o] : Ug[g][(k - 32) * 32 + o];
        Wstack[idx] = (f16_t)v;
    } else if (idx < 9216) {
        int t = idx - 8192;
        int o = t >> 5, k = t & 31;
        thstack[o * 32 + k] = (k < 25) ? (f16_t)theta[k * 32 + o] : (f16_t)0.0f;
    }
}

// ---------------------------------------------------------------------------
// transpose 768x768 + f16x2s split: xT[q][p] = x[p][q] (dual, B of stage1);
// straight f16 single into XR rows 0..767 (A of stage2, T_0 = I) and into
// Cbf rows 0..767 cols 0..767 (T_0 = I both sides).
// ---------------------------------------------------------------------------
__global__ __launch_bounds__(256) void transpose_cvt2x(
    const float* __restrict__ in, f16_t* __restrict__ o1,
    f16_t* __restrict__ o2, f16_t* __restrict__ xr0,
    f16_t* __restrict__ Cbf)
{
    __shared__ float t[32][33];
    int x = threadIdx.x & 31, y = threadIdx.x >> 5;
    int bx = blockIdx.x * 32, by = blockIdx.y * 32;
#pragma unroll
    for (int r = 0; r < 4; ++r) {
        int p = by + y + 8 * r, q = bx + x;
        size_t oi = (size_t)p * DIM + q;
        float v = in[oi];
        t[y + 8 * r][x] = v;
        f16_t hv = (f16_t)v;
        xr0[oi] = hv;
        Cbf[(size_t)p * 3840 + q] = hv;
    }
    __syncthreads();
#pragma unroll
    for (int r = 0; r < 4; ++r) {
        float v = t[x][y + 8 * r];
        f16_t h1, h2;
        split2h(v, h1, h2);
        size_t o = (size_t)(bx + y + 8 * r) * DIM + by + x;
        o1[o] = h1; o2[o] = h2;
    }
}

// ---------------------------------------------------------------------------
// 2-product f16 MFMA GEMM engine, double-buffered LDS (B-transposed,
// k-contig), 128x96 block, BK=32, 4 waves, wave tile 64x48.
// __launch_bounds__(256,3): VGPR cap 170 (cap-128 spilled — R9).
// mode 1: f16 single out D1 (ldc) + optional D3 (ld 3840);
// mode 2: cheb T2 (v = 2*acc - P), dual out, dual stack via halfStride;
// mode 3: f16 single out (+coloff), supertile (nbx=32);
// mode 4: batched cheb T3+T4 (offset table; pass S0/S1 bases).
// ---------------------------------------------------------------------------
__global__ __launch_bounds__(256, 3) void gemm_bt_h2(
    const f16_t* __restrict__ A1,
    const f16_t* __restrict__ B1, const f16_t* __restrict__ B2,
    const f16_t* __restrict__ P1, const f16_t* __restrict__ P2,
    f16_t* __restrict__ D1, f16_t* __restrict__ D2, f16_t* __restrict__ D3,
    int K, int ldc, int mode, int nbx, int halfStride, int coloff)
{
    __shared__ __align__(16) f16_t sA[2][128 * 32];       // 2 x 8 KB
    __shared__ __align__(16) f16_t sB[2][2 * 96 * 32];    // 2 x 12 KB

    const int tid = threadIdx.x;

    int bx, by;
    size_t hoff = 0;
    int aoff = 0, boff = 0, poff = 0, doff = 0;
    if (mode == 3) {
        // supertile: 8 rows x 32 cols share A/B panels -> L2 reuse
        int g = blockIdx.x;
        int sup = g >> 8;                   // / (8*32)
        int rows0 = sup * 8;
        int H = 30 - rows0; if (H > 8) H = 8;
        int local = g - rows0 * nbx;
        by = rows0 + local % H;
        bx = local / H;
    } else if (mode == 4) {
        // T3 = 2*L@T2 - T1 (g<96), T4 = 2*T2@T2 - T0 (g>=96); Tr|Tc stacks
        int g = blockIdx.x;
        int t34 = g / 96, r = g % 96;
        int stack = r / 48, rr = r % 48;
        by = rr >> 3; bx = rr & 7;
        hoff = (size_t)stack * halfStride;
        if (t34 == 0) { aoff = MXK; boff = 2 * MXK; poff = MXK; doff = 3 * MXK; }
        else          { aoff = 2 * MXK; boff = 2 * MXK; poff = 0; doff = 4 * MXK; }
    } else {
        bx = blockIdx.x % nbx;
        by = blockIdx.x / nbx;
        if (mode == 2 && by >= 6) { by -= 6; hoff = (size_t)halfStride; }
    }
    const int m0 = by * 128, n0 = bx * 96;

    const f16_t* Asrc1 = A1 + hoff + aoff;
    const f16_t* Bsrc1 = B1 + hoff + boff;
    const f16_t* Bsrc2 = B2 + hoff + boff;
    const f16_t* Pq1 = P1 ? P1 + hoff + poff : nullptr;
    const f16_t* Pq2 = P2 ? P2 + hoff + poff : nullptr;
    f16_t* Dq1 = D1 + hoff + doff;
    f16_t* Dq2 = D2 ? D2 + hoff + doff : nullptr;

    const int lane = tid & 63, w4 = tid >> 6;
    const int wm = (w4 & 1) * 64, wn = (w4 >> 1) * 48;
    const int lm = lane & 15, quad = lane >> 4;
    const int psw = (quad ^ ((lm >> 1) & 3)) * 8;

    // A staging: 512 16B-slots (128 rows x 4 chunks), 2 calls
    const f16_t* gApt[2]; int aslot[2];
#pragma unroll
    for (int cc = 0; cc < 2; ++cc) {
        int s = cc * 256 + w4 * 64 + lane;   // 0..511
        int row = s >> 2, pos = s & 3;
        int chunk = pos ^ ((row >> 1) & 3);
        gApt[cc] = Asrc1 + (size_t)(m0 + row) * K + chunk * 8;
        aslot[cc] = s * 8;
    }
    // B staging: 768 slots (2 lev x 96 rows x 4 chunks), 3 calls
    const f16_t* gBpt[3]; int bslot[3];
#pragma unroll
    for (int cc = 0; cc < 3; ++cc) {
        int slot = cc * 256 + w4 * 64 + lane;
        int lev = slot >= 384 ? 1 : 0;
        int s = slot - lev * 384;
        int row = s >> 2, pos = s & 3;
        int chunk = pos ^ ((row >> 1) & 3);
        gBpt[cc] = (lev ? Bsrc2 : Bsrc1) + (size_t)(n0 + row) * K + chunk * 8;
        bslot[cc] = lev * 3072 + s * 8;
    }

    f32x4 acc1[4][3] = {};
    f32x4 acc2[4][3] = {};

    // preload K-chunk 0 into buffer 0
#pragma unroll
    for (int cc = 0; cc < 2; ++cc) gl_lds16(gApt[cc], &sA[0][aslot[cc]]);
#pragma unroll
    for (int cc = 0; cc < 3; ++cc) gl_lds16(gBpt[cc], &sB[0][bslot[cc]]);
    __syncthreads();

    int ib = 0;
    for (int kb = 0; kb < K; kb += 32, ib ^= 1) {
        // prefetch next chunk into the other buffer (overlaps MFMA below)
        if (kb + 32 < K) {
            int nb = ib ^ 1;
#pragma unroll
            for (int cc = 0; cc < 2; ++cc)
                gl_lds16(gApt[cc] + kb + 32, &sA[nb][aslot[cc]]);
#pragma unroll
            for (int cc = 0; cc < 3; ++cc)
                gl_lds16(gBpt[cc] + kb + 32, &sB[nb][bslot[cc]]);
        }

        f16x8 bfr[2][3];
#pragma unroll
        for (int l = 0; l < 2; ++l)
#pragma unroll
            for (int fn = 0; fn < 3; ++fn)
                bfr[l][fn] = *(const f16x8*)&sB[ib][l * 3072 +
                                                (wn + fn * 16 + lm) * 32 + psw];
#pragma unroll
        for (int fm = 0; fm < 4; ++fm) {
            f16x8 a1v = *(const f16x8*)&sA[ib][(wm + fm * 16 + lm) * 32 + psw];
#pragma unroll
            for (int fn = 0; fn < 3; ++fn) {
                acc2[fm][fn] = __builtin_amdgcn_mfma_f32_16x16x32_f16(
                    a1v, bfr[1][fn], acc2[fm][fn], 0, 0, 0);
                acc1[fm][fn] = __builtin_amdgcn_mfma_f32_16x16x32_f16(
                    a1v, bfr[0][fn], acc1[fm][fn], 0, 0, 0);
            }
        }
        // barrier: (a) all waves done reading buf ib (safe to overwrite at
        // kb+64), (b) vmcnt(0) drain -> buf ib^1 staged (loads overlapped
        // the MFMA section above)
        __syncthreads();
    }

    // epilogue: C/D layout col=lane&15, row=quad*4+reg  [verified m89/m91]
#pragma unroll
    for (int fm = 0; fm < 4; ++fm)
#pragma unroll
        for (int fn = 0; fn < 3; ++fn) {
            int col = n0 + wn + fn * 16 + lm;
#pragma unroll
            for (int r = 0; r < 4; ++r) {
                int row = m0 + wm + fm * 16 + quad * 4 + r;
                float val = acc1[fm][fn][r] + acc2[fm][fn][r] * RINV;
                if (mode == 3) {
                    Dq1[(size_t)row * ldc + coloff + col] = (f16_t)val;
                } else if (mode == 1) {
                    Dq1[(size_t)row * ldc + col] = (f16_t)val;
                    if (D3) D3[(size_t)row * 3840 + col] = (f16_t)val;
                } else {
                    size_t o = (size_t)row * ldc + col;
                    val = 2.0f * val -
                          ((float)Pq1[o] + (float)Pq2[o] * RINV);
                    f16_t h1, h2;
                    split2h(val, h1, h2);
                    Dq1[o] = h1; Dq2[o] = h2;
                }
            }
        }
}

// ---------------------------------------------------------------------------
// Gate kernel (all f16; c now f16 too). Block = 128 pixels.
// ---------------------------------------------------------------------------
__global__ __launch_bounds__(256) void gate_theta_mfma(
    const f16_t* __restrict__ Cbf, const f16_t* __restrict__ thstack,
    const float* __restrict__ bias, const f16_t* __restrict__ Wstack,
    const float* __restrict__ bfv, const float* __restrict__ biv,
    const float* __restrict__ bov, const float* __restrict__ bcv,
    const float* __restrict__ Wout, const float* __restrict__ bout,
    f16_t* __restrict__ h, f16_t* __restrict__ c, float* __restrict__ x,
    int first)
{
    __shared__ __align__(16) ushort_t sB[128 * 72];  // f16 bits [px][k]
    __shared__ float red[256];

    const int tid = threadIdx.x;
    const int lane = tid & 63, w4 = tid >> 6;
    const int wm = (w4 & 1) * 64, wn = (w4 >> 1) * 64;
    const int lm = lane & 15, quad = lane >> 4;
    const int m = blockIdx.x / 6;
    const int n0 = (blockIdx.x % 6) * 128;
    const int pbase = m * DIM + n0;

    f16x8 af[4][2];
#pragma unroll
    for (int fm = 0; fm < 4; ++fm)
#pragma unroll
        for (int kc = 0; kc < 2; ++kc)
            af[fm][kc] = *(const f16x8*)&Wstack[(wm + fm * 16 + lm) * 64 +
                                                kc * 32 + quad * 8];

    f16x8 bth[2];
#pragma unroll
    for (int fn = 0; fn < 2; ++fn)
        bth[fn] = *(const f16x8*)&thstack[(fn * 16 + lm) * 32 + quad * 8];

    {
        int px = tid >> 1, part = tid & 1;
        uint4 v0, v1;
        if (first) {
            v0.x = v0.y = v0.z = v0.w = 0u; v1 = v0;
        } else {
            const uint4* src = (const uint4*)&h[(size_t)(pbase + px) * 32 + part * 16];
            v0 = src[0]; v1 = src[1];
        }
        uint4* dst = (uint4*)&sB[px * 72 + 32 + part * 16];
        dst[0] = v0; dst[1] = v1;
    }

    const int pw = w4 * 32;
    f32x4 tacc[2][2] = {};
    {
        int aoff[8];
#pragma unroll
        for (int j = 0; j < 8; ++j) {
            int k = quad * 8 + j;
            int ij = k > 24 ? 24 : k;
            int i5 = (ij * 205) >> 10;
            int j5 = ij - i5 * 5;
            aoff[j] = (i5 * DIM + m) * 3840 + j5 * DIM + n0 + pw + lm;
        }
        f16x8 a0, a1;
#pragma unroll
        for (int j = 0; j < 8; ++j) {
            a0[j] = Cbf[(size_t)aoff[j]];
            a1[j] = Cbf[(size_t)aoff[j] + 16];
        }
#pragma unroll
        for (int fn = 0; fn < 2; ++fn) {
            tacc[0][fn] = __builtin_amdgcn_mfma_f32_16x16x32_f16(
                a0, bth[fn], tacc[0][fn], 0, 0, 0);
            tacc[1][fn] = __builtin_amdgcn_mfma_f32_16x16x32_f16(
                a1, bth[fn], tacc[1][fn], 0, 0, 0);
        }
    }
    {
        float b0 = bias[lm], b1 = bias[16 + lm];
#pragma unroll
        for (int fm2 = 0; fm2 < 2; ++fm2)
#pragma unroll
            for (int fn = 0; fn < 2; ++fn) {
                float bb = fn ? b1 : b0;
#pragma unroll
                for (int r = 0; r < 4; ++r) {
                    float v = tacc[fm2][fn][r] + bb;
                    f16_t hv = (f16_t)v;
                    sB[(pw + fm2 * 16 + quad * 4 + r) * 72 + fn * 16 + lm] =
                        __builtin_bit_cast(ushort_t, hv);
                }
            }
    }
    __syncthreads();

    f32x4 acc[4][4] = {};
#pragma unroll
    for (int kc = 0; kc < 2; ++kc) {
        f16x8 bfr[4];
#pragma unroll
        for (int fn = 0; fn < 4; ++fn)
            bfr[fn] = *(const f16x8*)&sB[(wn + fn * 16 + lm) * 72 +
                                         kc * 32 + quad * 8];
#pragma unroll
        for (int fm = 0; fm < 4; ++fm)
#pragma unroll
            for (int fn = 0; fn < 4; ++fn)
                acc[fm][fn] = __builtin_amdgcn_mfma_f32_16x16x32_f16(
                    af[fm][kc], bfr[fn], acc[fm][fn], 0, 0, 0);
    }

    const int o0 = (wm >> 2) + quad * 4;
    const float4 bgf = *(const float4*)&bfv[o0];
    const float4 bgi = *(const float4*)&biv[o0];
    const float4 bgo = *(const float4*)&bov[o0];
    const float4 bgc = *(const float4*)&bcv[o0];
    const float4 wo4 = *(const float4*)&Wout[o0];

#pragma unroll
    for (int fn = 0; fn < 4; ++fn) {
        int px = wn + fn * 16 + lm;
        size_t p = (size_t)(pbase + px);
        f16_t co16[4];
        if (first) {
            co16[0] = co16[1] = co16[2] = co16[3] = (f16_t)0.0f;
        } else {
            *(uint2*)co16 = *(const uint2*)&c[p * 32 + o0];
        }
        float bf4[4] = {bgf.x, bgf.y, bgf.z, bgf.w};
        float bi4[4] = {bgi.x, bgi.y, bgi.z, bgi.w};
        float bo4[4] = {bgo.x, bgo.y, bgo.z, bgo.w};
        float bc4[4] = {bgc.x, bgc.y, bgc.z, bgc.w};
        float wo[4] = {wo4.x, wo4.y, wo4.z, wo4.w};
        f16_t cn16[4], hn[4];
        float part = 0.f;
#pragma unroll
        for (int r = 0; r < 4; ++r) {
            float fg = sigm(acc[0][fn][r] + bf4[r]);
            float ig = sigm(acc[1][fn][r] + bi4[r]);
            float og = sigm(acc[2][fn][r] + bo4[r]);
            float gg = sigm(acc[3][fn][r] + bc4[r]);
            float cn = fg * (float)co16[r] + ig * gg;
            cn16[r] = (f16_t)cn;
            hn[r] = (f16_t)(og * sigm(cn));
            part = fmaf(cn, wo[r], part);
        }
        *(uint2*)&c[p * 32 + o0] = *(const uint2*)cn16;
        *(uint2*)&h[p * 32 + o0] = *(const uint2*)hn;
        part += __shfl_xor(part, 16, 64);
        part += __shfl_xor(part, 32, 64);
        if (quad == 0) red[px * 2 + (wm >> 6)] = part;
    }
    __syncthreads();
    if (tid < 128) {
        float v = red[tid * 2] + red[tid * 2 + 1] + bout[0];
        v = fminf(fmaxf(v, -15.f), 15.f);
        float e = __expf(2.f * v);
        x[pbase + tid] += (e - 1.f) * __builtin_amdgcn_rcpf(e + 1.f);
    }
}

// ---------------------------------------------------------------------------
extern "C" void kernel_launch(void* const* d_in, const int* in_sizes, int n_in,
                              void* d_out, int out_size, void* d_ws, size_t ws_size,
                              hipStream_t stream)
{
    const float* x_in  = (const float*)d_in[0];
    const float* Lrow  = (const float*)d_in[1];
    const float* Lcol  = (const float*)d_in[2];
    const float* theta = (const float*)d_in[3];
    const float* bias  = (const float*)d_in[4];
    const float* Wf = (const float*)d_in[5];
    const float* Uf = (const float*)d_in[6];
    const float* bf = (const float*)d_in[7];
    const float* Wi = (const float*)d_in[8];
    const float* Ui = (const float*)d_in[9];
    const float* bi = (const float*)d_in[10];
    const float* Wo = (const float*)d_in[11];
    const float* Uo = (const float*)d_in[12];
    const float* bo = (const float*)d_in[13];
    const float* Wc = (const float*)d_in[14];
    const float* Uc = (const float*)d_in[15];
    const float* bc = (const float*)d_in[16];
    const float* Wout = (const float*)d_in[17];
    const float* bout = (const float*)d_in[18];
    (void)in_sizes; (void)n_in; (void)out_size;

    float* out = (float*)d_out;   // working x buffer

    // ---- workspace pool (136.9 MB) ----
    f16_t* base = (f16_t*)d_ws;
    f16_t* Cbf  = base;                              // 14,745,600 f16
    f16_t* h    = Cbf + 14745600;                    // 18,874,368 f16
    f16_t* c    = h + 18874368;                      // 18,874,368 f16
    f16_t* S0   = c + 18874368;                      // 2*STK (Tr | Tc)
    f16_t* S1   = S0 + 2 * STK;
    f16_t* XR0  = S1 + 2 * STK;                      // STK (single level)
    f16_t* Wstack  = XR0 + STK;                      // 8192
    f16_t* thstack = Wstack + 8192;                  // 1024
    f16_t* xT0  = thstack + 1024;                    // MXK
    f16_t* xT1  = xT0 + MXK;                         // MXK
    if (ws_size < (size_t)136857600) return;

    hipMemcpyAsync(out, x_in, (size_t)MXK * 4, hipMemcpyDeviceToDevice, stream);

    prep_gate<<<36, 256, 0, stream>>>(Wf, Wi, Wo, Wc, Uf, Ui, Uo, Uc, theta,
                                      Wstack, thstack);
    init_split<<<MXK / 256, 256, 0, stream>>>(Lrow, Lcol, S0, S1);
    // T2 = 2*L@L - T0 (Tr+Tc dual stack): A = L hi, B = L dual
    gemm_bt_h2<<<96, 256, 0, stream>>>(
        S0 + MXK, S0 + MXK, S1 + MXK, S0, S1,
        S0 + 2 * MXK, S1 + 2 * MXK, nullptr,
        DIM, DIM, 2, 8, STK, 0);
    // T3 = 2*L@T2 - T1  AND  T4 = 2*T2@T2 - T0, both stacks, one launch
    gemm_bt_h2<<<192, 256, 0, stream>>>(
        S0, S0, S1, S0, S1, S0, S1, nullptr,
        DIM, DIM, 4, 8, STK, 0);

    for (int it = 0; it < 3; ++it) {
        // xT dual split + x f16 into XR rows 0..767 + Cbf rows 0..767 (j0)
        transpose_cvt2x<<<dim3(24, 24), 256, 0, stream>>>(out, xT0, xT1,
                                                          XR0, Cbf);
        // stage1: XR rows 768..3839 = T_{1..4} @ x (f16 single out);
        // also Cbf j0 rows 768+
        gemm_bt_h2<<<192, 256, 0, stream>>>(
            S0 + MXK, xT0, xT1,
            nullptr, nullptr,
            XR0 + MXK, nullptr, Cbf + (size_t)DIM * 3840,
            DIM, DIM, 1, 8, 0, 0);
        // stage2: Cbf cols 768.. = XR @ Tc_{1..4}^T (M=3840, N=3072, K=768)
        gemm_bt_h2<<<960, 256, 0, stream>>>(
            XR0, S0 + STK + MXK, S1 + STK + MXK,
            nullptr, nullptr,
            Cbf, nullptr, nullptr, DIM, 3840, 3, 32, 0, DIM);
        // gates: theta-MFMA + gate-MFMA + LSTM + x += tanh(c.Wout+b)
        gate_theta_mfma<<<4608, 256, 0, stream>>>(
            Cbf, thstack, bias, Wstack,
            bf, bi, bo, bc, Wout, bout, h, c, out, it == 0 ? 1 : 0);
    }
}

// Round 16
// 550.408 us; speedup vs baseline: 1.0274x; 1.0274x over previous
//
#include <hip/hip_runtime.h>
#include <hip/hip_bf16.h>
#include <stdint.h>

// ---------------------------------------------------------------------------
// MGCNN on MI355X — 2-product f16 MFMA conv + all-f16 MFMA gate kernel.
//
// Number format: B operands dual-level (b = b1 + b2*2^-11), A single f16.
//   acc1 = sum a1*b1 ; acc2 = sum a1*b2 ; D = acc1 + acc2*2^-11
//
// R16: gate theta A-gather via LDS. R15 showed the gate is latency-bound
// (MfmaUtil 5.7%, VALU 39%, Occ 18%): 32 dependent scalar global u16 loads
// per lane formed the critical path. Now the 6.4 KB Cbf working set
// (25 ij x 128 px) is staged with 400 coalesced uint4 loads before the
// existing first barrier; A-frags become cheap ds_read_u16.
// ---------------------------------------------------------------------------

#define DIM 768
#define MXK 589824        // 768*768
#define STK 2949120       // 5*768*768
#define RSCALE 2048.0f
#define RINV   (1.0f / 2048.0f)

typedef _Float16 f16x8 __attribute__((ext_vector_type(8)));
typedef float f32x4 __attribute__((ext_vector_type(4)));
typedef unsigned short ushort_t;
typedef _Float16 f16_t;

__device__ __forceinline__ float sigm(float v) {
    float e = __expf(-v);
    return __builtin_amdgcn_rcpf(1.0f + e);   // raw v_rcp_f32, ~1 ulp
}
__device__ __forceinline__ void split2h(float f, f16_t& h1, f16_t& h2) {
    h1 = (f16_t)f;
    float r = f - (float)h1;
    h2 = (f16_t)(r * RSCALE);
}

// async 16B global->LDS (LDS dest = wave-uniform base + lane*16)
__device__ __forceinline__ void gl_lds16(const f16_t* g, f16_t* l) {
    auto gp = reinterpret_cast<const __attribute__((address_space(1))) uint32_t*>(
        reinterpret_cast<uintptr_t>(g));
    auto lp = reinterpret_cast<__attribute__((address_space(3))) uint32_t*>(
        reinterpret_cast<uintptr_t>(l));
    __builtin_amdgcn_global_load_lds(gp, lp, 16, 0, 0);
}

// ---------------------------------------------------------------------------
// init: T0 = I, T1 = L  ->  f16x2s, Tr stack then Tc stack per level
// ---------------------------------------------------------------------------
__global__ __launch_bounds__(256) void init_split(
    const float* __restrict__ Lrow, const float* __restrict__ Lcol,
    f16_t* __restrict__ S0, f16_t* __restrict__ S1)
{
    int idx = blockIdx.x * 256 + threadIdx.x;
    int p = idx / DIM, m = idx % DIM;
    f16_t eye = (p == m) ? (f16_t)1.0f : (f16_t)0.0f;
    S0[idx] = eye; S1[idx] = (f16_t)0.0f;
    S0[STK + idx] = eye; S1[STK + idx] = (f16_t)0.0f;
    f16_t h1, h2;
    split2h(Lrow[idx], h1, h2);
    S0[MXK + idx] = h1; S1[MXK + idx] = h2;
    split2h(Lcol[idx], h1, h2);
    S0[STK + MXK + idx] = h1; S1[STK + MXK + idx] = h2;
}

// ---------------------------------------------------------------------------
// prep: Wstack f16 [128 R][64 k] and thstack f16 [32 o][32 k=ij] (k>=25 -> 0)
// ---------------------------------------------------------------------------
__global__ __launch_bounds__(256) void prep_gate(
    const float* __restrict__ Wf, const float* __restrict__ Wi,
    const float* __restrict__ Wo, const float* __restrict__ Wc,
    const float* __restrict__ Uf, const float* __restrict__ Ui,
    const float* __restrict__ Uo, const float* __restrict__ Uc,
    const float* __restrict__ theta,
    f16_t* __restrict__ Wstack, f16_t* __restrict__ thstack)
{
    int idx = blockIdx.x * 256 + threadIdx.x;
    if (idx < 8192) {
        int R = idx >> 6, k = idx & 63;
        int g = (R >> 4) & 3, o = (R >> 6) * 16 + (R & 15);
        const float* Wg[4] = {Wf, Wi, Wo, Wc};
        const float* Ug[4] = {Uf, Ui, Uo, Uc};
        float v = (k < 32) ? Wg[g][k * 32 + o] : Ug[g][(k - 32) * 32 + o];
        Wstack[idx] = (f16_t)v;
    } else if (idx < 9216) {
        int t = idx - 8192;
        int o = t >> 5, k = t & 31;
        thstack[o * 32 + k] = (k < 25) ? (f16_t)theta[k * 32 + o] : (f16_t)0.0f;
    }
}

// ---------------------------------------------------------------------------
// transpose 768x768 + f16x2s split: xT[q][p] = x[p][q] (dual, B of stage1);
// straight f16 single into XR rows 0..767 (A of stage2, T_0 = I) and into
// Cbf rows 0..767 cols 0..767 (T_0 = I both sides).
// ---------------------------------------------------------------------------
__global__ __launch_bounds__(256) void transpose_cvt2x(
    const float* __restrict__ in, f16_t* __restrict__ o1,
    f16_t* __restrict__ o2, f16_t* __restrict__ xr0,
    f16_t* __restrict__ Cbf)
{
    __shared__ float t[32][33];
    int x = threadIdx.x & 31, y = threadIdx.x >> 5;
    int bx = blockIdx.x * 32, by = blockIdx.y * 32;
#pragma unroll
    for (int r = 0; r < 4; ++r) {
        int p = by + y + 8 * r, q = bx + x;
        size_t oi = (size_t)p * DIM + q;
        float v = in[oi];
        t[y + 8 * r][x] = v;
        f16_t hv = (f16_t)v;
        xr0[oi] = hv;
        Cbf[(size_t)p * 3840 + q] = hv;
    }
    __syncthreads();
#pragma unroll
    for (int r = 0; r < 4; ++r) {
        float v = t[x][y + 8 * r];
        f16_t h1, h2;
        split2h(v, h1, h2);
        size_t o = (size_t)(bx + y + 8 * r) * DIM + by + x;
        o1[o] = h1; o2[o] = h2;
    }
}

// ---------------------------------------------------------------------------
// 2-product f16 MFMA GEMM engine, double-buffered LDS (B-transposed,
// k-contig), 128x96 block, BK=32, 4 waves, wave tile 64x48.
// __launch_bounds__(256,3): VGPR cap 170 (cap-128 spilled — R9).
// mode 1: f16 single out D1 (ldc) + optional D3 (ld 3840);
// mode 2: cheb T2 (v = 2*acc - P), dual out, dual stack via halfStride;
// mode 3: f16 single out (+coloff), supertile (nbx=32);
// mode 4: batched cheb T3+T4 (offset table; pass S0/S1 bases).
// ---------------------------------------------------------------------------
__global__ __launch_bounds__(256, 3) void gemm_bt_h2(
    const f16_t* __restrict__ A1,
    const f16_t* __restrict__ B1, const f16_t* __restrict__ B2,
    const f16_t* __restrict__ P1, const f16_t* __restrict__ P2,
    f16_t* __restrict__ D1, f16_t* __restrict__ D2, f16_t* __restrict__ D3,
    int K, int ldc, int mode, int nbx, int halfStride, int coloff)
{
    __shared__ __align__(16) f16_t sA[2][128 * 32];       // 2 x 8 KB
    __shared__ __align__(16) f16_t sB[2][2 * 96 * 32];    // 2 x 12 KB

    const int tid = threadIdx.x;

    int bx, by;
    size_t hoff = 0;
    int aoff = 0, boff = 0, poff = 0, doff = 0;
    if (mode == 3) {
        // supertile: 8 rows x 32 cols share A/B panels -> L2 reuse
        int g = blockIdx.x;
        int sup = g >> 8;                   // / (8*32)
        int rows0 = sup * 8;
        int H = 30 - rows0; if (H > 8) H = 8;
        int local = g - rows0 * nbx;
        by = rows0 + local % H;
        bx = local / H;
    } else if (mode == 4) {
        // T3 = 2*L@T2 - T1 (g<96), T4 = 2*T2@T2 - T0 (g>=96); Tr|Tc stacks
        int g = blockIdx.x;
        int t34 = g / 96, r = g % 96;
        int stack = r / 48, rr = r % 48;
        by = rr >> 3; bx = rr & 7;
        hoff = (size_t)stack * halfStride;
        if (t34 == 0) { aoff = MXK; boff = 2 * MXK; poff = MXK; doff = 3 * MXK; }
        else          { aoff = 2 * MXK; boff = 2 * MXK; poff = 0; doff = 4 * MXK; }
    } else {
        bx = blockIdx.x % nbx;
        by = blockIdx.x / nbx;
        if (mode == 2 && by >= 6) { by -= 6; hoff = (size_t)halfStride; }
    }
    const int m0 = by * 128, n0 = bx * 96;

    const f16_t* Asrc1 = A1 + hoff + aoff;
    const f16_t* Bsrc1 = B1 + hoff + boff;
    const f16_t* Bsrc2 = B2 + hoff + boff;
    const f16_t* Pq1 = P1 ? P1 + hoff + poff : nullptr;
    const f16_t* Pq2 = P2 ? P2 + hoff + poff : nullptr;
    f16_t* Dq1 = D1 + hoff + doff;
    f16_t* Dq2 = D2 ? D2 + hoff + doff : nullptr;

    const int lane = tid & 63, w4 = tid >> 6;
    const int wm = (w4 & 1) * 64, wn = (w4 >> 1) * 48;
    const int lm = lane & 15, quad = lane >> 4;
    const int psw = (quad ^ ((lm >> 1) & 3)) * 8;

    // A staging: 512 16B-slots (128 rows x 4 chunks), 2 calls
    const f16_t* gApt[2]; int aslot[2];
#pragma unroll
    for (int cc = 0; cc < 2; ++cc) {
        int s = cc * 256 + w4 * 64 + lane;   // 0..511
        int row = s >> 2, pos = s & 3;
        int chunk = pos ^ ((row >> 1) & 3);
        gApt[cc] = Asrc1 + (size_t)(m0 + row) * K + chunk * 8;
        aslot[cc] = s * 8;
    }
    // B staging: 768 slots (2 lev x 96 rows x 4 chunks), 3 calls
    const f16_t* gBpt[3]; int bslot[3];
#pragma unroll
    for (int cc = 0; cc < 3; ++cc) {
        int slot = cc * 256 + w4 * 64 + lane;
        int lev = slot >= 384 ? 1 : 0;
        int s = slot - lev * 384;
        int row = s >> 2, pos = s & 3;
        int chunk = pos ^ ((row >> 1) & 3);
        gBpt[cc] = (lev ? Bsrc2 : Bsrc1) + (size_t)(n0 + row) * K + chunk * 8;
        bslot[cc] = lev * 3072 + s * 8;
    }

    f32x4 acc1[4][3] = {};
    f32x4 acc2[4][3] = {};

    // preload K-chunk 0 into buffer 0
#pragma unroll
    for (int cc = 0; cc < 2; ++cc) gl_lds16(gApt[cc], &sA[0][aslot[cc]]);
#pragma unroll
    for (int cc = 0; cc < 3; ++cc) gl_lds16(gBpt[cc], &sB[0][bslot[cc]]);
    __syncthreads();

    int ib = 0;
    for (int kb = 0; kb < K; kb += 32, ib ^= 1) {
        // prefetch next chunk into the other buffer (overlaps MFMA below)
        if (kb + 32 < K) {
            int nb = ib ^ 1;
#pragma unroll
            for (int cc = 0; cc < 2; ++cc)
                gl_lds16(gApt[cc] + kb + 32, &sA[nb][aslot[cc]]);
#pragma unroll
            for (int cc = 0; cc < 3; ++cc)
                gl_lds16(gBpt[cc] + kb + 32, &sB[nb][bslot[cc]]);
        }

        f16x8 bfr[2][3];
#pragma unroll
        for (int l = 0; l < 2; ++l)
#pragma unroll
            for (int fn = 0; fn < 3; ++fn)
                bfr[l][fn] = *(const f16x8*)&sB[ib][l * 3072 +
                                                (wn + fn * 16 + lm) * 32 + psw];
#pragma unroll
        for (int fm = 0; fm < 4; ++fm) {
            f16x8 a1v = *(const f16x8*)&sA[ib][(wm + fm * 16 + lm) * 32 + psw];
#pragma unroll
            for (int fn = 0; fn < 3; ++fn) {
                acc2[fm][fn] = __builtin_amdgcn_mfma_f32_16x16x32_f16(
                    a1v, bfr[1][fn], acc2[fm][fn], 0, 0, 0);
                acc1[fm][fn] = __builtin_amdgcn_mfma_f32_16x16x32_f16(
                    a1v, bfr[0][fn], acc1[fm][fn], 0, 0, 0);
            }
        }
        // barrier: (a) all waves done reading buf ib (safe to overwrite at
        // kb+64), (b) vmcnt(0) drain -> buf ib^1 staged (loads overlapped
        // the MFMA section above)
        __syncthreads();
    }

    // epilogue: C/D layout col=lane&15, row=quad*4+reg  [verified m89/m91]
#pragma unroll
    for (int fm = 0; fm < 4; ++fm)
#pragma unroll
        for (int fn = 0; fn < 3; ++fn) {
            int col = n0 + wn + fn * 16 + lm;
#pragma unroll
            for (int r = 0; r < 4; ++r) {
                int row = m0 + wm + fm * 16 + quad * 4 + r;
                float val = acc1[fm][fn][r] + acc2[fm][fn][r] * RINV;
                if (mode == 3) {
                    Dq1[(size_t)row * ldc + coloff + col] = (f16_t)val;
                } else if (mode == 1) {
                    Dq1[(size_t)row * ldc + col] = (f16_t)val;
                    if (D3) D3[(size_t)row * 3840 + col] = (f16_t)val;
                } else {
                    size_t o = (size_t)row * ldc + col;
                    val = 2.0f * val -
                          ((float)Pq1[o] + (float)Pq2[o] * RINV);
                    f16_t h1, h2;
                    split2h(val, h1, h2);
                    Dq1[o] = h1; Dq2[o] = h2;
                }
            }
        }
}

// ---------------------------------------------------------------------------
// Gate kernel (all f16). Block = 128 pixels. Cbf working set staged via LDS
// (coalesced uint4), A-frags gathered from LDS instead of scalar global.
// ---------------------------------------------------------------------------
__global__ __launch_bounds__(256) void gate_theta_mfma(
    const f16_t* __restrict__ Cbf, const f16_t* __restrict__ thstack,
    const float* __restrict__ bias, const f16_t* __restrict__ Wstack,
    const float* __restrict__ bfv, const float* __restrict__ biv,
    const float* __restrict__ bov, const float* __restrict__ bcv,
    const float* __restrict__ Wout, const float* __restrict__ bout,
    f16_t* __restrict__ h, f16_t* __restrict__ c, float* __restrict__ x,
    int first)
{
    __shared__ __align__(16) ushort_t sB[128 * 72];  // f16 bits [px][k]
    __shared__ __align__(16) ushort_t sC[25 * 128];  // Cbf tile [ij][px]
    __shared__ float red[256];

    const int tid = threadIdx.x;
    const int lane = tid & 63, w4 = tid >> 6;
    const int wm = (w4 & 1) * 64, wn = (w4 >> 1) * 64;
    const int lm = lane & 15, quad = lane >> 4;
    const int m = blockIdx.x / 6;
    const int n0 = (blockIdx.x % 6) * 128;
    const int pbase = m * DIM + n0;

    f16x8 af[4][2];
#pragma unroll
    for (int fm = 0; fm < 4; ++fm)
#pragma unroll
        for (int kc = 0; kc < 2; ++kc)
            af[fm][kc] = *(const f16x8*)&Wstack[(wm + fm * 16 + lm) * 64 +
                                                kc * 32 + quad * 8];

    f16x8 bth[2];
#pragma unroll
    for (int fn = 0; fn < 2; ++fn)
        bth[fn] = *(const f16x8*)&thstack[(fn * 16 + lm) * 32 + quad * 8];

    // stage Cbf tile: 25 ij x 128 px, 400 uint4 (coalesced, parallel issue)
#pragma unroll
    for (int cc = 0; cc < 2; ++cc) {
        int s = cc * 256 + tid;
        if (s < 400) {
            int ij = s >> 4, f = s & 15;
            int i5 = (ij * 205) >> 10;       // ij/5 for ij<32
            int j5 = ij - i5 * 5;
            size_t ga = (size_t)(i5 * DIM + m) * 3840 + j5 * DIM + n0 + f * 8;
            *(uint4*)&sC[ij * 128 + f * 8] = *(const uint4*)&Cbf[ga];
        }
    }
    // stage h -> sB[px][32..63]
    {
        int px = tid >> 1, part = tid & 1;
        uint4 v0, v1;
        if (first) {
            v0.x = v0.y = v0.z = v0.w = 0u; v1 = v0;
        } else {
            const uint4* src = (const uint4*)&h[(size_t)(pbase + px) * 32 + part * 16];
            v0 = src[0]; v1 = src[1];
        }
        uint4* dst = (uint4*)&sB[px * 72 + 32 + part * 16];
        dst[0] = v0; dst[1] = v1;
    }
    __syncthreads();   // sC + h staged

    const int pw = w4 * 32;
    f32x4 tacc[2][2] = {};
    {
        const f16_t* sCf = (const f16_t*)sC;
        f16x8 a0, a1;
#pragma unroll
        for (int j = 0; j < 8; ++j) {
            int k = quad * 8 + j;
            int ij = k > 24 ? 24 : k;
            a0[j] = sCf[ij * 128 + pw + lm];
            a1[j] = sCf[ij * 128 + pw + 16 + lm];
        }
#pragma unroll
        for (int fn = 0; fn < 2; ++fn) {
            tacc[0][fn] = __builtin_amdgcn_mfma_f32_16x16x32_f16(
                a0, bth[fn], tacc[0][fn], 0, 0, 0);
            tacc[1][fn] = __builtin_amdgcn_mfma_f32_16x16x32_f16(
                a1, bth[fn], tacc[1][fn], 0, 0, 0);
        }
    }
    {
        float b0 = bias[lm], b1 = bias[16 + lm];
#pragma unroll
        for (int fm2 = 0; fm2 < 2; ++fm2)
#pragma unroll
            for (int fn = 0; fn < 2; ++fn) {
                float bb = fn ? b1 : b0;
#pragma unroll
                for (int r = 0; r < 4; ++r) {
                    float v = tacc[fm2][fn][r] + bb;
                    f16_t hv = (f16_t)v;
                    sB[(pw + fm2 * 16 + quad * 4 + r) * 72 + fn * 16 + lm] =
                        __builtin_bit_cast(ushort_t, hv);
                }
            }
    }
    __syncthreads();

    f32x4 acc[4][4] = {};
#pragma unroll
    for (int kc = 0; kc < 2; ++kc) {
        f16x8 bfr[4];
#pragma unroll
        for (int fn = 0; fn < 4; ++fn)
            bfr[fn] = *(const f16x8*)&sB[(wn + fn * 16 + lm) * 72 +
                                         kc * 32 + quad * 8];
#pragma unroll
        for (int fm = 0; fm < 4; ++fm)
#pragma unroll
            for (int fn = 0; fn < 4; ++fn)
                acc[fm][fn] = __builtin_amdgcn_mfma_f32_16x16x32_f16(
                    af[fm][kc], bfr[fn], acc[fm][fn], 0, 0, 0);
    }

    const int o0 = (wm >> 2) + quad * 4;
    const float4 bgf = *(const float4*)&bfv[o0];
    const float4 bgi = *(const float4*)&biv[o0];
    const float4 bgo = *(const float4*)&bov[o0];
    const float4 bgc = *(const float4*)&bcv[o0];
    const float4 wo4 = *(const float4*)&Wout[o0];

#pragma unroll
    for (int fn = 0; fn < 4; ++fn) {
        int px = wn + fn * 16 + lm;
        size_t p = (size_t)(pbase + px);
        f16_t co16[4];
        if (first) {
            co16[0] = co16[1] = co16[2] = co16[3] = (f16_t)0.0f;
        } else {
            *(uint2*)co16 = *(const uint2*)&c[p * 32 + o0];
        }
        float bf4[4] = {bgf.x, bgf.y, bgf.z, bgf.w};
        float bi4[4] = {bgi.x, bgi.y, bgi.z, bgi.w};
        float bo4[4] = {bgo.x, bgo.y, bgo.z, bgo.w};
        float bc4[4] = {bgc.x, bgc.y, bgc.z, bgc.w};
        float wo[4] = {wo4.x, wo4.y, wo4.z, wo4.w};
        f16_t cn16[4], hn[4];
        float part = 0.f;
#pragma unroll
        for (int r = 0; r < 4; ++r) {
            float fg = sigm(acc[0][fn][r] + bf4[r]);
            float ig = sigm(acc[1][fn][r] + bi4[r]);
            float og = sigm(acc[2][fn][r] + bo4[r]);
            float gg = sigm(acc[3][fn][r] + bc4[r]);
            float cn = fg * (float)co16[r] + ig * gg;
            cn16[r] = (f16_t)cn;
            hn[r] = (f16_t)(og * sigm(cn));
            part = fmaf(cn, wo[r], part);
        }
        *(uint2*)&c[p * 32 + o0] = *(const uint2*)cn16;
        *(uint2*)&h[p * 32 + o0] = *(const uint2*)hn;
        part += __shfl_xor(part, 16, 64);
        part += __shfl_xor(part, 32, 64);
        if (quad == 0) red[px * 2 + (wm >> 6)] = part;
    }
    __syncthreads();
    if (tid < 128) {
        float v = red[tid * 2] + red[tid * 2 + 1] + bout[0];
        v = fminf(fmaxf(v, -15.f), 15.f);
        float e = __expf(2.f * v);
        x[pbase + tid] += (e - 1.f) * __builtin_amdgcn_rcpf(e + 1.f);
    }
}

// ---------------------------------------------------------------------------
extern "C" void kernel_launch(void* const* d_in, const int* in_sizes, int n_in,
                              void* d_out, int out_size, void* d_ws, size_t ws_size,
                              hipStream_t stream)
{
    const float* x_in  = (const float*)d_in[0];
    const float* Lrow  = (const float*)d_in[1];
    const float* Lcol  = (const float*)d_in[2];
    const float* theta = (const float*)d_in[3];
    const float* bias  = (const float*)d_in[4];
    const float* Wf = (const float*)d_in[5];
    const float* Uf = (const float*)d_in[6];
    const float* bf = (const float*)d_in[7];
    const float* Wi = (const float*)d_in[8];
    const float* Ui = (const float*)d_in[9];
    const float* bi = (const float*)d_in[10];
    const float* Wo = (const float*)d_in[11];
    const float* Uo = (const float*)d_in[12];
    const float* bo = (const float*)d_in[13];
    const float* Wc = (const float*)d_in[14];
    const float* Uc = (const float*)d_in[15];
    const float* bc = (const float*)d_in[16];
    const float* Wout = (const float*)d_in[17];
    const float* bout = (const float*)d_in[18];
    (void)in_sizes; (void)n_in; (void)out_size;

    float* out = (float*)d_out;   // working x buffer

    // ---- workspace pool (136.9 MB) ----
    f16_t* base = (f16_t*)d_ws;
    f16_t* Cbf  = base;                              // 14,745,600 f16
    f16_t* h    = Cbf + 14745600;                    // 18,874,368 f16
    f16_t* c    = h + 18874368;                      // 18,874,368 f16
    f16_t* S0   = c + 18874368;                      // 2*STK (Tr | Tc)
    f16_t* S1   = S0 + 2 * STK;
    f16_t* XR0  = S1 + 2 * STK;                      // STK (single level)
    f16_t* Wstack  = XR0 + STK;                      // 8192
    f16_t* thstack = Wstack + 8192;                  // 1024
    f16_t* xT0  = thstack + 1024;                    // MXK
    f16_t* xT1  = xT0 + MXK;                         // MXK
    if (ws_size < (size_t)136857600) return;

    hipMemcpyAsync(out, x_in, (size_t)MXK * 4, hipMemcpyDeviceToDevice, stream);

    prep_gate<<<36, 256, 0, stream>>>(Wf, Wi, Wo, Wc, Uf, Ui, Uo, Uc, theta,
                                      Wstack, thstack);
    init_split<<<MXK / 256, 256, 0, stream>>>(Lrow, Lcol, S0, S1);
    // T2 = 2*L@L - T0 (Tr+Tc dual stack): A = L hi, B = L dual
    gemm_bt_h2<<<96, 256, 0, stream>>>(
        S0 + MXK, S0 + MXK, S1 + MXK, S0, S1,
        S0 + 2 * MXK, S1 + 2 * MXK, nullptr,
        DIM, DIM, 2, 8, STK, 0);
    // T3 = 2*L@T2 - T1  AND  T4 = 2*T2@T2 - T0, both stacks, one launch
    gemm_bt_h2<<<192, 256, 0, stream>>>(
        S0, S0, S1, S0, S1, S0, S1, nullptr,
        DIM, DIM, 4, 8, STK, 0);

    for (int it = 0; it < 3; ++it) {
        // xT dual split + x f16 into XR rows 0..767 + Cbf rows 0..767 (j0)
        transpose_cvt2x<<<dim3(24, 24), 256, 0, stream>>>(out, xT0, xT1,
                                                          XR0, Cbf);
        // stage1: XR rows 768..3839 = T_{1..4} @ x (f16 single out);
        // also Cbf j0 rows 768+
        gemm_bt_h2<<<192, 256, 0, stream>>>(
            S0 + MXK, xT0, xT1,
            nullptr, nullptr,
            XR0 + MXK, nullptr, Cbf + (size_t)DIM * 3840,
            DIM, DIM, 1, 8, 0, 0);
        // stage2: Cbf cols 768.. = XR @ Tc_{1..4}^T (M=3840, N=3072, K=768)
        gemm_bt_h2<<<960, 256, 0, stream>>>(
            XR0, S0 + STK + MXK, S1 + STK + MXK,
            nullptr, nullptr,
            Cbf, nullptr, nullptr, DIM, 3840, 3, 32, 0, DIM);
        // gates: theta-MFMA + gate-MFMA + LSTM + x += tanh(c.Wout+b)
        gate_theta_mfma<<<4608, 256, 0, stream>>>(
            Cbf, thstack, bias, Wstack,
            bf, bi, bo, bc, Wout, bout, h, c, out, it == 0 ? 1 : 0);
    }
}